// Round 6
// baseline (201.413 us; speedup 1.0000x reference)
//
#include <hip/hip_runtime.h>
#include <hip/hip_bf16.h>
#include <stdint.h>

#define DOUT 1024
#define NMAX 16384

#define BM 256
#define BN 128
#define LDSBUF 24576   // per K-step buffer: A 16384 B + B 8192 B (BK=32)
#define BOFFS 16384    // B region offset within a buffer

typedef __attribute__((ext_vector_type(8))) short short8;
typedef __attribute__((ext_vector_type(4))) float floatx4;

__device__ __forceinline__ unsigned short f2bf(float f) {
  union { float f; uint32_t u; } v;
  v.f = f;
  return (unsigned short)((v.u + 0x7FFFu + ((v.u >> 16) & 1u)) >> 16);  // RNE
}

// pack 4 fp32 -> 4 bf16 (RNE) using HW packed cvt
__device__ __forceinline__ ushort4 cvt4(float4 v) {
  __hip_bfloat162 p0 = __float22bfloat162_rn(make_float2(v.x, v.y));
  __hip_bfloat162 p1 = __float22bfloat162_rn(make_float2(v.z, v.w));
  union { __hip_bfloat162 h[2]; ushort4 s; } u;
  u.h[0] = p0; u.h[1] = p1;
  return u.s;
}

// ---------------------------------------------------------------------------
// classify tokens (blocks 0..63) + convert weights to bf16 (blocks 64..).
// ---------------------------------------------------------------------------
__global__ __launch_bounds__(256) void classify_cvt_kernel(
    const int* __restrict__ idx, int* __restrict__ cnt,
    int* __restrict__ bucket, int* __restrict__ blocal, int N,
    const float* __restrict__ w0, const float* __restrict__ w1,
    const float* __restrict__ w2, unsigned short* __restrict__ wb0,
    unsigned short* __restrict__ wb1, unsigned short* __restrict__ wb2) {
  if (blockIdx.x < 64) {
    int n = blockIdx.x * 256 + threadIdx.x;
    int lane = threadIdx.x & 63;
    int c = -1, v = 0;
    if (n < N) {
      v = idx[n];
      c = (v < 20000) ? 0 : ((v < 40000) ? 1 : 2);
    }
#pragma unroll
    for (int k = 0; k < 3; ++k) {
      unsigned long long m = __ballot(c == k);
      if (c == k) {
        int leader = __ffsll((unsigned long long)m) - 1;
        int base = 0;
        if (lane == leader) base = atomicAdd(&cnt[k], (int)__popcll(m));
        base = __shfl(base, leader);
        int rank = (int)__popcll(m & ((1ull << (unsigned)lane) - 1ull));
        int lo = (k == 0) ? 0 : (k == 1) ? 20000 : 40000;
        bucket[k * NMAX + base + rank] = n;
        blocal[k * NMAX + base + rank] = v - lo;
      }
    }
  } else {
    int i = (blockIdx.x - 64) * 256 + threadIdx.x;
    if (i >= 344064) return;
    const float4* src;
    ushort4* dst;
    if (i < 262144) {            // w0: 1024x1024
      src = (const float4*)w0 + i;
      dst = (ushort4*)wb0 + i;
    } else if (i < 327680) {     // w1: 1024x256
      src = (const float4*)w1 + (i - 262144);
      dst = (ushort4*)wb1 + (i - 262144);
    } else {                     // w2: 1024x64
      src = (const float4*)w2 + (i - 327680);
      dst = (ushort4*)wb2 + (i - 327680);
    }
    float4 v = *src;
    ushort4 o;
    o.x = f2bf(v.x); o.y = f2bf(v.y); o.z = f2bf(v.z); o.w = f2bf(v.w);
    *dst = o;
  }
}

// ---------------------------------------------------------------------------
// Gather bucketed embedding rows -> packed bf16 A matrices.
//   Abf layout: [cnt0 x 1024][cnt1 x 256][cnt2 x 64] (+256-row slack)
// ---------------------------------------------------------------------------
__global__ __launch_bounds__(256) void gather_kernel(
    const float* __restrict__ emb0, const float* __restrict__ emb1,
    const float* __restrict__ emb2, const int* __restrict__ cnt,
    const int* __restrict__ blocal, unsigned short* __restrict__ Abf) {
  const int b = blockIdx.x;
  const int c0 = cnt[0], c1 = cnt[1], c2 = cnt[2];
  const float* emb;
  const int* bl;
  int H, count, baseRow, lg;
  size_t off;
  if (b < 4096) {
    emb = emb0; bl = blocal; H = 1024; count = c0; off = 0;
    baseRow = b * 4; lg = 6;
  } else if (b < 5120) {
    emb = emb1; bl = blocal + NMAX; H = 256; count = c1;
    off = (size_t)c0 * 1024; baseRow = (b - 4096) * 16; lg = 4;
  } else {
    emb = emb2; bl = blocal + 2 * NMAX; H = 64; count = c2;
    off = (size_t)c0 * 1024 + (size_t)c1 * 256; baseRow = (b - 5120) * 64; lg = 2;
  }
  const int tid = threadIdx.x;
  const int r = baseRow + (tid >> lg);
  if (r >= count) return;
  const int tpr = 1 << lg;              // threads per row (H/16)
  const int e = (tid & (tpr - 1)) * 4;  // first float4, element offset
  const int stride = tpr * 4;           // elements between chunks
  const float* src = emb + (size_t)bl[r] * H + e;
  unsigned short* d = Abf + off + (size_t)r * H + e;
#pragma unroll
  for (int j = 0; j < 4; ++j) {
    float4 v = *(const float4*)(src + j * stride);
    *(ushort4*)(d + j * stride) = cvt4(v);
  }
}

// ---------------------------------------------------------------------------
// One 256x128 output tile, BK=32, 3-deep pipeline in 72KB LDS -> 2 blocks/CU
// (the round-5 lesson: every 1-block/CU variant pinned at ~40us with all
// pipes idle; TLP, not ILP, closes latency gaps). Counted vmcnt (6/3/0 with
// 3 loads/stage), XOR bank-swizzle both-sides (0 conflicts measured r3),
// load-once fragments (8 ds_read_b128 -> 16 MFMA per K-step).
// ---------------------------------------------------------------------------
template <int H>
__device__ __forceinline__ void tile_compute(
    const unsigned short* __restrict__ A, const unsigned short* __restrict__ B,
    int count, const int* __restrict__ bucket, float* __restrict__ out,
    char* lds, int* rowTok, int by, int bx) {
  constexpr int NT = H / 32;
  const int m0 = by * BM;
  const int n0 = bx * BN;

  const int tid = threadIdx.x;
  const int wave = tid >> 6;
  const int lane = tid & 63;
  const int quad = lane >> 4;
  const int l16 = lane & 15;
  const int wm = wave & 3;   // 4 m-waves: rows [wm*64, wm*64+64)
  const int wn = wave >> 2;  // 2 n-waves: cols [wn*64, wn*64+64)

  if (tid < BM) {
    int m = m0 + tid;
    rowTok[tid] = (m < count) ? bucket[m] : -1;
  }

  // staging: per-thread logical slot after the involution (64B rows, 4x16B)
  const int dl = wave * 1024 + lane * 16;          // region-relative dest byte
  const int lswz = dl ^ (((dl >> 7) & 3) << 4);    // logical slot
  const int rA = lswz >> 6;                        // row 0..127
  const int ck = (lswz >> 4) & 3;                  // 16B chunk in 64B row
  const char* Abyte = (const char*)A;
  const char* Bbyte = (const char*)B;
  const size_t aSrc0 = ((size_t)(m0 + rA) * H) * 2 + ck * 16;
  const size_t aSrc1 = ((size_t)(m0 + 128 + rA) * H) * 2 + ck * 16;
  const size_t bSrc = ((size_t)(n0 + rA) * H) * 2 + ck * 16;

  // stage one BK=32 K-step (3 x global_load_lds w=16 per thread)
  auto stage = [&](int kt, char* buf) {
    const size_t kb = (size_t)kt * 64;  // 32 k-elems * 2B
    __builtin_amdgcn_global_load_lds(
        (const __attribute__((address_space(1))) void*)(Abyte + aSrc0 + kb),
        (__attribute__((address_space(3))) void*)(buf + wave * 1024), 16, 0, 0);
    __builtin_amdgcn_global_load_lds(
        (const __attribute__((address_space(1))) void*)(Abyte + aSrc1 + kb),
        (__attribute__((address_space(3))) void*)(buf + 8192 + wave * 1024), 16, 0, 0);
    __builtin_amdgcn_global_load_lds(
        (const __attribute__((address_space(1))) void*)(Bbyte + bSrc + kb),
        (__attribute__((address_space(3))) void*)(buf + BOFFS + wave * 1024), 16, 0, 0);
  };

  // fragment read offsets (K-invariant, swizzled)
  int offA[4], offB[4];
#pragma unroll
  for (int i = 0; i < 4; ++i) {
    int ba = (wm * 64 + i * 16 + l16) * 64 + quad * 16;
    offA[i] = ba ^ (((ba >> 7) & 3) << 4);
    int bb = (wn * 64 + i * 16 + l16) * 64 + quad * 16;
    offB[i] = BOFFS + (bb ^ (((bb >> 7) & 3) << 4));
  }

  floatx4 acc[4][4];
#pragma unroll
  for (int i = 0; i < 4; ++i)
#pragma unroll
    for (int j = 0; j < 4; ++j) acc[i][j] = (floatx4){0.f, 0.f, 0.f, 0.f};

  auto compute = [&](const char* buf) {
    short8 a[4], b[4];
#pragma unroll
    for (int i = 0; i < 4; ++i) {
      a[i] = *(const short8*)(buf + offA[i]);
      b[i] = *(const short8*)(buf + offB[i]);
    }
    __builtin_amdgcn_s_setprio(1);
#pragma unroll
    for (int i = 0; i < 4; ++i)
#pragma unroll
      for (int j = 0; j < 4; ++j)
        acc[i][j] = __builtin_amdgcn_mfma_f32_16x16x32_bf16(
            a[i], b[j], acc[i][j], 0, 0, 0);
    __builtin_amdgcn_s_setprio(0);
  };

  if constexpr (NT >= 3) {
    // prologue: 3-deep
    stage(0, lds);
    stage(1, lds + LDSBUF);
    stage(2, lds + 2 * LDSBUF);
    char* b0 = lds;
    char* b1 = lds + LDSBUF;
    char* b2 = lds + 2 * LDSBUF;
#pragma unroll 1
    for (int kt = 0; kt < NT - 3; ++kt) {
      asm volatile("s_waitcnt vmcnt(6)" ::: "memory");
      asm volatile("s_barrier" ::: "memory");
      compute(b0);
      asm volatile("s_waitcnt lgkmcnt(0)" ::: "memory");  // reads retired
      asm volatile("s_barrier" ::: "memory");             // before overwrite
      stage(kt + 3, b0);
      char* t = b0; b0 = b1; b1 = b2; b2 = t;
    }
    // tail kt = NT-3, NT-2, NT-1 (no more staging)
    asm volatile("s_waitcnt vmcnt(6)" ::: "memory");
    asm volatile("s_barrier" ::: "memory");
    compute(b0);
    asm volatile("s_waitcnt vmcnt(3)" ::: "memory");
    asm volatile("s_barrier" ::: "memory");
    compute(b1);
    asm volatile("s_waitcnt vmcnt(0)" ::: "memory");
    asm volatile("s_barrier" ::: "memory");
    compute(b2);
  } else {  // NT == 2 (H = 64)
    stage(0, lds);
    stage(1, lds + LDSBUF);
    asm volatile("s_waitcnt vmcnt(3)" ::: "memory");
    asm volatile("s_barrier" ::: "memory");
    compute(lds);
    asm volatile("s_waitcnt vmcnt(0)" ::: "memory");
    asm volatile("s_barrier" ::: "memory");
    compute(lds + LDSBUF);
  }

  // epilogue: scatter rows (C/D: col=lane&15, row=quad*4+reg)
  const int colBase = n0 + wn * 64 + l16;
#pragma unroll
  for (int mi = 0; mi < 4; ++mi) {
#pragma unroll
    for (int r = 0; r < 4; ++r) {
      int tok = rowTok[wm * 64 + mi * 16 + quad * 4 + r];
      if (tok >= 0) {
        float* o = out + (size_t)tok * DOUT + colBase;
#pragma unroll
        for (int ni = 0; ni < 4; ++ni) o[ni * 16] = acc[mi][ni][r];
      }
    }
  }
}

// ---------------------------------------------------------------------------
// Persistent work-stealing GEMM: 512 blocks (2/CU now that LDS = 73KB),
// global atomic tile queue ordered heavy-first (c0, then c1, then c2).
// ---------------------------------------------------------------------------
__global__ __launch_bounds__(512, 4) void gemm_persist(
    const unsigned short* __restrict__ Abf,
    const unsigned short* __restrict__ wb0,
    const unsigned short* __restrict__ wb1,
    const unsigned short* __restrict__ wb2, const int* __restrict__ cnt,
    const int* __restrict__ bucket, float* __restrict__ out,
    int* __restrict__ tileCtr) {
  __shared__ __align__(16) char lds[3 * LDSBUF + BM * 4 + 16];
  int* rowTok = (int*)(lds + 3 * LDSBUF);
  int* curTile = (int*)(lds + 3 * LDSBUF + BM * 4);

  const int c0 = cnt[0], c1 = cnt[1], c2 = cnt[2];
  const int nt0 = (c0 + BM - 1) / BM;
  const int nt1 = (c1 + BM - 1) / BM;
  const int nt2 = (c2 + BM - 1) / BM;
  const int T0 = nt0 * 8, T1 = nt1 * 8, T2 = nt2 * 8;
  const int total = T0 + T1 + T2;
  const size_t o1 = (size_t)c0 * 1024;
  const size_t o2 = o1 + (size_t)c1 * 256;

  for (;;) {
    __syncthreads();  // prev tile fully done (epilogue + all LDS reads)
    if (threadIdx.x == 0) *curTile = atomicAdd(tileCtr, 1);
    __syncthreads();
    const int t = *curTile;
    if (t >= total) return;
    if (t < T0) {
      tile_compute<1024>(Abf, wb0, c0, bucket, out, lds, rowTok, t >> 3, t & 7);
    } else if (t < T0 + T1) {
      const int u = t - T0;
      tile_compute<256>(Abf + o1, wb1, c1, bucket + NMAX, out, lds, rowTok,
                        u >> 3, u & 7);
    } else {
      const int u = t - T0 - T1;
      tile_compute<64>(Abf + o2, wb2, c2, bucket + 2 * NMAX, out, lds, rowTok,
                       u >> 3, u & 7);
    }
  }
}

extern "C" void kernel_launch(void* const* d_in, const int* in_sizes, int n_in,
                              void* d_out, int out_size, void* d_ws, size_t ws_size,
                              hipStream_t stream) {
  const int* idx = (const int*)d_in[0];
  const float* emb0 = (const float*)d_in[1];
  const float* w0 = (const float*)d_in[2];
  const float* emb1 = (const float*)d_in[3];
  const float* w1 = (const float*)d_in[4];
  const float* emb2 = (const float*)d_in[5];
  const float* w2 = (const float*)d_in[6];
  float* out = (float*)d_out;
  const int N = in_sizes[0];  // 16384

  // ---- workspace layout ----
  char* ws = (char*)d_ws;
  int* cnt = (int*)ws;                              // 64 B (cnt[0..2], tileCtr at [8])
  int* bucket = (int*)(ws + 1024);                  // 3*NMAX ints
  int* blocal = bucket + 3 * NMAX;                  // 3*NMAX ints
  size_t off = 1024 + (size_t)6 * NMAX * 4;
  off = (off + 255) & ~(size_t)255;
  unsigned short* wb0 = (unsigned short*)(ws + off); off += (size_t)DOUT * 1024 * 2;
  unsigned short* wb1 = (unsigned short*)(ws + off); off += (size_t)DOUT * 256 * 2;
  unsigned short* wb2 = (unsigned short*)(ws + off); off += (size_t)DOUT * 64 * 2;
  off = (off + 255) & ~(size_t)255;
  unsigned short* Abf = (unsigned short*)(ws + off);
  off += (size_t)(NMAX + 256) * 1024 * 2;  // packed A + BM-row tile slack

  hipMemsetAsync(cnt, 0, 16 * sizeof(int), stream);  // zeroes cnt incl. tileCtr

  // classify (64 blocks) + weight cvt (1344 blocks)
  classify_cvt_kernel<<<64 + 1344, 256, 0, stream>>>(
      idx, cnt, bucket, blocal, N, w0, w1, w2, wb0, wb1, wb2);

  // gather bucketed emb rows -> packed bf16 A
  gather_kernel<<<5376, 256, 0, stream>>>(emb0, emb1, emb2, cnt, blocal, Abf);

  // persistent work-stealing GEMM: 512 blocks (2/CU), heavy-first queue
  gemm_persist<<<512, 512, 0, stream>>>(Abf, wb0, wb1, wb2, cnt, bucket, out,
                                        cnt + 8);
}